// Round 12
// baseline (112.610 us; speedup 1.0000x reference)
//
#include <hip/hip_runtime.h>
#include <hip/hip_bf16.h>

typedef __bf16 bf8 __attribute__((ext_vector_type(8)));
typedef unsigned short u16x8 __attribute__((ext_vector_type(8)));
typedef float f32x4 __attribute__((ext_vector_type(4)));
typedef float f32x2 __attribute__((ext_vector_type(2)));
typedef unsigned int u32x4 __attribute__((ext_vector_type(4)));

union FragU { u16x8 u; bf8 b; u32x4 q; };
union BiasU { f32x4 f; u32x4 q; };

struct __attribute__((packed, aligned(4))) F4u { float v[4]; };
struct __attribute__((packed, aligned(4))) F2u { float v[2]; };

static __device__ __forceinline__ f32x4 MM(const FragU& a, const FragU& b, f32x4 c) {
  return __builtin_amdgcn_mfma_f32_16x16x32_bf16(a.b, b.b, c, 0, 0, 0);
}

#define NBATCH 524288
#define NCH 2                  // chains per wave
#define SPB (NCH * 16 * 4)     // samples per block-iter = 128
#define NTIL (NBATCH / SPB)    // 4096
#define GRID 1024              // 4 blocks/CU (weights in LDS -> ~128 regs -> 4 waves/SIMD)
#define ITERS (NTIL / GRID)    // 4
#define NFRAG 37

// ============================ PREP KERNEL ============================
__global__ __launch_bounds__(64) void cdann_prep(
    const float* __restrict__ gWf1, const float* __restrict__ gbf1,
    const float* __restrict__ gWf2, const float* __restrict__ gbf2,
    const float* __restrict__ gWt1, const float* __restrict__ gbt1,
    const float* __restrict__ gWt2, const float* __restrict__ gbt2,
    const float* __restrict__ gWp1, const float* __restrict__ gbp1,
    const float* __restrict__ gWp2, const float* __restrict__ gbp2,
    const float* __restrict__ gWp3, const float* __restrict__ gbp3,
    const float* __restrict__ gWc1, const float* __restrict__ gbc1,
    const float* __restrict__ gWc2, const float* __restrict__ gbc2,
    const float* __restrict__ gWc3, const float* __restrict__ gbc3,
    u32x4* __restrict__ ws)
{
  const int lane = (int)threadIdx.x & 63;
  const int fid = (int)blockIdx.x;
  const int g = lane >> 4;
  const int c15 = lane & 15;

  auto colF2 = [](int nt, int m) -> int {
    if (nt < 2) return 8 * (m >> 2) + 4 * nt + (m & 3);
    const int gm = m >> 2, r = m & 3;
    if (gm == 0) return 32 + r;
    if (gm == 1) return 36 + r;
    if (gm == 2 && r < 2) return 40 + r;
    return -1;
  };

  if (fid >= 34) {                       // f2 bias slices (f32x4 per lane)
    const int nt = fid - 34;
    BiasU b;
#pragma unroll
    for (int r = 0; r < 4; ++r) {
      const int col = colF2(nt, g * 4 + r);
      b.f[r] = (col >= 0) ? gbf2[col] : 0.f;
    }
    ws[fid * 64 + lane] = b.q;
    return;
  }

  auto v_f1 = [&](int k, int m, int nt) -> float {
    const int n = 32 * (nt >> 1) + 8 * (m >> 2) + 4 * (nt & 1) + (m & 3);
    if (k < 30) return gWf1[k * 64 + n];
    if (k == 30) return gbf1[n];
    return 0.f;
  };
  auto v_f2 = [&](int k, int m, int nt) -> float {
    const int col = colF2(nt, m);
    return (col >= 0) ? gWf2[k * 42 + col] : 0.f;
  };
  auto ffea = [](int v) -> int {
    if (v < 36) return v;
    if (v == 36) return -2;
    if (v >= 40 && v <= 43) return v - 4;
    if (v == 48 || v == 49) return v - 8;
    return -1;
  };
  auto v_q = [&](int k, int m, int nt) -> float {
    const int i = ffea(k);
    if (i == -1) return 0.f;
    const int gm = m >> 2;
    const int u = 4 * nt + (m & 3);
    const int head = u / 5;
    const int f = 5 * gm + (u % 5);
    if (head == 0) return (i == -2) ? gbt1[f] : gWt1[i * 20 + f];
    if (head == 1) return (i == -2) ? gbp1[f] : gWp1[i * 20 + f];
    if (head == 2) return (i == -2) ? gbc1[f] : gWc1[i * 20 + f];
    return (i == -2) ? gbc1[20 + f] : gWc1[(42 + i) * 20 + f];
  };
  auto v_tp = [&](int k, int m, int nt) -> float {
    const int ks = k >> 5, j = k & 7, gk = (k >> 3) & 3;
    const int gm = m >> 2;
    const int u = 4 * nt + (m & 3);
    const int isP2 = (u < 5);
    const int cp = 5 * gm + u;
    const int isT2 = (!isP2 && gm == 0 && (u == 5 || u == 6));
    const int ct = u - 5;
    if (ks == 0) {
      if (j < 5) { const int i = 5 * gk + j; return isT2 ? gWt2[i * 2 + ct] : 0.f; }
      if (j == 7 && gk == 0) { if (isT2) return gbt2[ct]; if (isP2) return gbp2[cp]; }
      return 0.f;
    } else {
      if (j < 5) { const int i = 5 * gk + j; return isP2 ? gWp2[i * 20 + cp] : 0.f; }
      return 0.f;
    }
  };
  auto v_cc = [&](int k, int m, int nt) -> float {
    const int ks = k >> 5, j = k & 7, gk = (k >> 3) & 3;
    const int gm = m >> 2;
    const int u = 4 * nt + (m & 3);
    const int isE0 = (u < 5);
    const int isE1 = (u >= 5 && u < 10);
    const int c0 = 5 * gm + u;
    const int c1 = 5 * gm + (u - 5);
    if (ks == 0) {
      if (j < 5) { const int i = 5 * gk + j; return isE0 ? gWc2[i * 20 + c0] : 0.f; }
      if (j == 7 && gk == 0) { if (isE0) return gbc2[c0]; if (isE1) return gbc2[20 + c1]; }
      return 0.f;
    } else {
      if (j < 5) { const int i = 5 * gk + j; return isE1 ? gWc2[(20 + i) * 20 + c1] : 0.f; }
      return 0.f;
    }
  };
  auto v_o = [&](int k, int m, int nt) -> float {
    const int ks = k >> 5, j = k & 7, gk = (k >> 3) & 3;
    const int gm = m >> 2, r = m & 3;
    int kind = -1, c = 0;   // 0=pd, 1=cd0, 2=cd1
    if (nt == 0) {
      if (gm == 0) { kind = 0; c = r; }
      else if (gm == 1) { if (r < 2) { kind = 0; c = 4 + r; } else { kind = 1; c = r - 2; } }
      else if (gm == 2) { kind = 1; c = 2 + r; }
      else { kind = 2; c = r; }
    } else {
      if (gm == 0 && r < 2) { kind = 2; c = 4 + r; }
    }
    if (kind < 0) return 0.f;
    if (ks == 0) {
      if (j < 5) { const int i = 5 * gk + j; return (kind == 0) ? gWp3[i * 6 + c] : 0.f; }
      if (j < 7) { const int i = 5 * gk + (j - 5); return (kind == 2) ? gWc3[(20 + i) * 6 + c] : 0.f; }
      if (gk == 0) {
        if (kind == 0) return gbp3[c];
        if (kind == 1) return gbc3[c];
        return gbc3[6 + c];
      }
      return 0.f;
    } else {
      if (j < 5) { const int i = 5 * gk + j; return (kind == 1) ? gWc3[i * 6 + c] : 0.f; }
      const int i = 5 * gk + 2 + (j - 5);
      return (kind == 2) ? gWc3[(20 + i) * 6 + c] : 0.f;
    }
  };

  int ks, nt, which;
  if (fid < 4)       { ks = 0;                nt = fid;            which = 0; }
  else if (fid < 10) { int t = fid - 4;  ks = t / 3; nt = t % 3;   which = 1; }
  else if (fid < 20) { int t = fid - 10; ks = t / 5; nt = t % 5;   which = 2; }
  else if (fid < 24) { int t = fid - 20; ks = t / 2; nt = t % 2;   which = 3; }
  else if (fid < 30) { int t = fid - 24; ks = t / 3; nt = t % 3;   which = 4; }
  else               { int t = fid - 30; ks = t / 2; nt = t % 2;   which = 5; }

  FragU f;
#pragma unroll
  for (int j = 0; j < 8; ++j) {
    const int k = ks * 32 + g * 8 + j;
    float v;
    switch (which) {
      case 0: v = v_f1(k, c15, nt); break;
      case 1: v = v_f2(k, c15, nt); break;
      case 2: v = v_q(k, c15, nt); break;
      case 3: v = v_tp(k, c15, nt); break;
      case 4: v = v_cc(k, c15, nt); break;
      default: v = v_o(k, c15, nt); break;
    }
    f.b[j] = (__bf16)v;
  }
  ws[fid * 64 + lane] = f.q;
}

// ============================ MAIN KERNEL ============================
// All 37 weight fragments live in LDS (block-shared, 37 KB) and are
// ds_read just-in-time; each read feeds both chains' MFMAs. Register
// footprint = working state only (~120 incl. acc) -> 4 waves/SIMD at
// __launch_bounds__(256,4). This flips R3's pin-everything strategy,
// which capped the chip at 2 waves/SIMD (R5/R6/R9-R11 evidence).
__global__ __launch_bounds__(256, 4) void cdann_fwd(
    const float* __restrict__ gx, const int* __restrict__ gy,
    const u32x4* __restrict__ ws, float* __restrict__ gout)
{
  __shared__ __align__(16) u32x4 lfr[NFRAG * 64];   // 37888 B
  const int tid = (int)threadIdx.x;
  const int lane = tid & 63;
  const int w = tid >> 6;
  const int g = lane >> 4;
  const int c15 = lane & 15;

  for (int i = tid; i < NFRAG * 64; i += 256) lfr[i] = ws[i];
  __syncthreads();   // lfr read-only afterwards (no more barriers)

  auto LF = [&](int fid) { FragU t; t.q = lfr[fid * 64 + lane]; return t; };

  const f32x4 zf = {0.f, 0.f, 0.f, 0.f};
  const __bf16 one = (__bf16)1.0f;
  const __bf16 zero = (__bf16)0.0f;
  float* const outT = gout;
  float* const outP = gout + (size_t)2 * NBATCH;
  float* const outC = gout + (size_t)8 * NBATCH;

  // ---- x/y prefetch (bf16-packed, 8 regs + 2) ----
  FragU bxp[NCH];
  int ys[NCH];
  auto loadx = [&](int it) {
    const int base = it * SPB + w * (NCH * 16) + c15;
#pragma unroll
    for (int c = 0; c < NCH; ++c) {
      const int s = base + c * 16;
      const float* xp = gx + (size_t)s * 30 + g * 8;
      float t[8];
      if (g < 3) {
        F4u a0 = *(const F4u*)xp; F4u a1 = *(const F4u*)(xp + 4);
#pragma unroll
        for (int j = 0; j < 4; ++j) { t[j] = a0.v[j]; t[4 + j] = a1.v[j]; }
      } else {
        F4u a0 = *(const F4u*)xp; F2u a1 = *(const F2u*)(xp + 4);
#pragma unroll
        for (int j = 0; j < 4; ++j) t[j] = a0.v[j];
        t[4] = a1.v[0]; t[5] = a1.v[1];
        t[6] = 1.0f; t[7] = 0.0f;   // k=30 const1 (bias fold), k=31 zero
      }
#pragma unroll
      for (int j = 0; j < 8; ++j) bxp[c].b[j] = (__bf16)t[j];
      ys[c] = gy[s];
    }
  };

  loadx((int)blockIdx.x);

  for (int ii = 0; ii < ITERS; ++ii) {
    const int it = (int)blockIdx.x + ii * GRID;
    const int base = it * SPB + w * (NCH * 16) + c15;

    FragU bxA = bxp[0], bxB = bxp[1];
    const int yA = ys[0], yB = ys[1];

    if (ii + 1 < ITERS) loadx(it + GRID);   // next iter's loads fly under compute

    // ---- f1: each LDS frag read feeds both chains ----
    f32x4 aHA[4], aHB[4];
#pragma unroll
    for (int nt = 0; nt < 4; ++nt) {
      FragU t = LF(nt);
      aHA[nt] = MM(t, bxA, zf);
      aHB[nt] = MM(t, bxB, zf);
    }
    FragU bhA0, bhA1, bhB0, bhB1;
#pragma unroll
    for (int j = 0; j < 8; ++j) {
      bhA0.b[j] = (__bf16)fmaxf(aHA[j >> 2][j & 3], 0.f);
      bhA1.b[j] = (__bf16)fmaxf(aHA[2 + (j >> 2)][j & 3], 0.f);
      bhB0.b[j] = (__bf16)fmaxf(aHB[j >> 2][j & 3], 0.f);
      bhB1.b[j] = (__bf16)fmaxf(aHB[2 + (j >> 2)][j & 3], 0.f);
    }

    // ---- f2 ----
    f32x4 aFA[3], aFB[3];
#pragma unroll
    for (int nt = 0; nt < 3; ++nt) {
      FragU t0 = LF(4 + nt), t1 = LF(7 + nt);
      aFA[nt] = MM(t1, bhA1, MM(t0, bhA0, zf));
      aFB[nt] = MM(t1, bhB1, MM(t0, bhB0, zf));
    }
    FragU bf0[2], bf1[2];
    {
      BiasU b0, b1, b2;
      b0.q = lfr[34 * 64 + lane]; b1.q = lfr[35 * 64 + lane]; b2.q = lfr[36 * 64 + lane];
#pragma unroll
      for (int j = 0; j < 8; ++j) {
        const float bb = (j >> 2) ? b1.f[j & 3] : b0.f[j & 3];
        bf0[0].b[j] = (__bf16)fmaxf(aFA[j >> 2][j & 3] + bb, 0.f);
        bf0[1].b[j] = (__bf16)fmaxf(aFB[j >> 2][j & 3] + bb, 0.f);
      }
#pragma unroll
      for (int j = 0; j < 4; ++j) {
        bf1[0].b[j] = (__bf16)fmaxf(aFA[2][j] + b2.f[j], 0.f);
        bf1[1].b[j] = (__bf16)fmaxf(aFB[2][j] + b2.f[j], 0.f);
      }
      const __bf16 c1v = (g == 0) ? one : zero;
      bf1[0].b[4] = c1v; bf1[0].b[5] = zero; bf1[0].b[6] = zero; bf1[0].b[7] = zero;
      bf1[1].b[4] = c1v; bf1[1].b[5] = zero; bf1[1].b[6] = zero; bf1[1].b[7] = zero;
    }

    // ---- quad heads: shared frag reads, both chains ----
    f32x4 aQA[5], aQB[5];
#pragma unroll
    for (int nt = 0; nt < 5; ++nt) {
      FragU t0 = LF(10 + nt), t1 = LF(15 + nt);
      aQA[nt] = MM(t1, bf1[0], MM(t0, bf0[0], zf));
      aQB[nt] = MM(t1, bf1[1], MM(t0, bf0[1], zf));
    }
    FragU tp0[2], tp1[2], cc0[2], cc1[2];
    {
      const __bf16 c1v = (g == 0) ? one : zero;
#pragma unroll
      for (int j = 0; j < 5; ++j) {
        tp0[0].b[j] = (__bf16)fmaxf(aQA[j >> 2][j & 3], 0.f);
        tp1[0].b[j] = (__bf16)fmaxf(aQA[(5 + j) >> 2][(5 + j) & 3], 0.f);
        cc0[0].b[j] = (__bf16)fmaxf(aQA[(10 + j) >> 2][(10 + j) & 3], 0.f);
        cc1[0].b[j] = (__bf16)fmaxf(aQA[(15 + j) >> 2][(15 + j) & 3], 0.f);
        tp0[1].b[j] = (__bf16)fmaxf(aQB[j >> 2][j & 3], 0.f);
        tp1[1].b[j] = (__bf16)fmaxf(aQB[(5 + j) >> 2][(5 + j) & 3], 0.f);
        cc0[1].b[j] = (__bf16)fmaxf(aQB[(10 + j) >> 2][(10 + j) & 3], 0.f);
        cc1[1].b[j] = (__bf16)fmaxf(aQB[(15 + j) >> 2][(15 + j) & 3], 0.f);
      }
#pragma unroll
      for (int ci = 0; ci < 2; ++ci) {
        tp0[ci].b[5] = zero; tp0[ci].b[6] = zero; tp0[ci].b[7] = c1v;
        tp1[ci].b[5] = zero; tp1[ci].b[6] = zero; tp1[ci].b[7] = zero;
        cc0[ci].b[5] = zero; cc0[ci].b[6] = zero; cc0[ci].b[7] = c1v;
        cc1[ci].b[5] = zero; cc1[ci].b[6] = zero; cc1[ci].b[7] = zero;
      }
    }

    // ---- [t2|p2] and [c2e0|c2e1]: shared frag reads ----
    f32x4 aT[2][2];
#pragma unroll
    for (int nt = 0; nt < 2; ++nt) {
      FragU t0 = LF(20 + nt), t1 = LF(22 + nt);
#pragma unroll
      for (int ci = 0; ci < 2; ++ci)
        aT[ci][nt] = MM(t1, tp1[ci], MM(t0, tp0[ci], zf));
    }
    f32x4 aC[2][3];
#pragma unroll
    for (int nt = 0; nt < 3; ++nt) {
      FragU t0 = LF(24 + nt), t1 = LF(27 + nt);
#pragma unroll
      for (int ci = 0; ci < 2; ++ci)
        aC[ci][nt] = MM(t1, cc1[ci], MM(t0, cc0[ci], zf));
    }

    // ---- final B-frags ----
    FragU f50[2], f51[2];
    f32x2 t2v[2];
#pragma unroll
    for (int ci = 0; ci < 2; ++ci) {
#pragma unroll
      for (int j = 0; j < 4; ++j) {
        f50[ci].b[j] = (__bf16)fmaxf(aT[ci][0][j], 0.f);
        f51[ci].b[j] = (__bf16)fmaxf(aC[ci][0][j], 0.f);
      }
      f50[ci].b[4] = (__bf16)fmaxf(aT[ci][1][0], 0.f);
      f50[ci].b[5] = (__bf16)fmaxf(aC[ci][1][1], 0.f);
      f50[ci].b[6] = (__bf16)fmaxf(aC[ci][1][2], 0.f);
      f50[ci].b[7] = (g == 0) ? one : zero;
      f51[ci].b[4] = (__bf16)fmaxf(aC[ci][1][0], 0.f);
      f51[ci].b[5] = (__bf16)fmaxf(aC[ci][1][3], 0.f);
      f51[ci].b[6] = (__bf16)fmaxf(aC[ci][2][0], 0.f);
      f51[ci].b[7] = (__bf16)fmaxf(aC[ci][2][1], 0.f);
      t2v[ci][0] = aT[ci][1][1]; t2v[ci][1] = aT[ci][1][2];
    }

    // ---- [pd|cd0|cd1]: shared frag reads ----
    f32x4 aO0[2], aO1[2];
    {
      FragU o0 = LF(30), o1 = LF(32);
#pragma unroll
      for (int ci = 0; ci < 2; ++ci)
        aO0[ci] = MM(o1, f51[ci], MM(o0, f50[ci], zf));
    }
    {
      FragU o0 = LF(31), o1 = LF(33);
#pragma unroll
      for (int ci = 0; ci < 2; ++ci)
        aO1[ci] = MM(o1, f51[ci], MM(o0, f50[ci], zf));
    }

    // ---- stores ----
#pragma unroll
    for (int ci = 0; ci < 2; ++ci) {
      const int s = base + ci * 16;
      const int y = ci ? yB : yA;
      const f32x4 aO0v = aO0[ci], aO1v = aO1[ci];
      if (g == 0) {
        *(f32x2*)(outT + (size_t)s * 2) = t2v[ci];
        f32x2 pa = {aO0v[0], aO0v[1]}, pb = {aO0v[2], aO0v[3]};
        *(f32x2*)(outP + (size_t)s * 6) = pa;
        *(f32x2*)(outP + (size_t)s * 6 + 2) = pb;
        if (y) { f32x2 cv = {aO1v[0], aO1v[1]}; *(f32x2*)(outC + (size_t)s * 6 + 4) = cv; }
      } else if (g == 1) {
        f32x2 pc = {aO0v[0], aO0v[1]};
        *(f32x2*)(outP + (size_t)s * 6 + 4) = pc;
        if (!y) { f32x2 cv = {aO0v[2], aO0v[3]}; *(f32x2*)(outC + (size_t)s * 6) = cv; }
      } else if (g == 2) {
        if (!y) {
          f32x2 ca = {aO0v[0], aO0v[1]}, cb = {aO0v[2], aO0v[3]};
          *(f32x2*)(outC + (size_t)s * 6 + 2) = ca;
          *(f32x2*)(outC + (size_t)s * 6 + 4) = cb;
        }
      } else {
        if (y) {
          f32x2 ca = {aO0v[0], aO0v[1]}, cb = {aO0v[2], aO0v[3]};
          *(f32x2*)(outC + (size_t)s * 6) = ca;
          *(f32x2*)(outC + (size_t)s * 6 + 2) = cb;
        }
      }
    }
  }
}

extern "C" void kernel_launch(void* const* d_in, const int* in_sizes, int n_in,
                              void* d_out, int out_size, void* d_ws, size_t ws_size,
                              hipStream_t stream) {
  (void)in_sizes; (void)n_in; (void)ws_size; (void)out_size;
  const float* gx  = (const float*)d_in[0];
  const int*   gy  = (const int*)d_in[1];
  const float* Wf1 = (const float*)d_in[2];  const float* bf1 = (const float*)d_in[3];
  const float* Wf2 = (const float*)d_in[4];  const float* bf2 = (const float*)d_in[5];
  const float* Wt1 = (const float*)d_in[6];  const float* bt1 = (const float*)d_in[7];
  const float* Wt2 = (const float*)d_in[8];  const float* bt2 = (const float*)d_in[9];
  const float* Wp1 = (const float*)d_in[10]; const float* bp1 = (const float*)d_in[11];
  const float* Wp2 = (const float*)d_in[12]; const float* bp2 = (const float*)d_in[13];
  const float* Wp3 = (const float*)d_in[14]; const float* bp3 = (const float*)d_in[15];
  const float* Wc1 = (const float*)d_in[16]; const float* bc1 = (const float*)d_in[17];
  const float* Wc2 = (const float*)d_in[18]; const float* bc2 = (const float*)d_in[19];
  const float* Wc3 = (const float*)d_in[20]; const float* bc3 = (const float*)d_in[21];
  float* out = (float*)d_out;
  u32x4* ws = (u32x4*)d_ws;

  cdann_prep<<<dim3(NFRAG), dim3(64), 0, stream>>>(
      Wf1, bf1, Wf2, bf2, Wt1, bt1, Wt2, bt2,
      Wp1, bp1, Wp2, bp2, Wp3, bp3, Wc1, bc1, Wc2, bc2, Wc3, bc3, ws);

  cdann_fwd<<<dim3(GRID), dim3(256), 0, stream>>>(gx, gy, ws, out);
}

// Round 13
// 38.732 us; speedup vs baseline: 2.9074x; 2.9074x over previous
//
#include <hip/hip_runtime.h>
#include <hip/hip_bf16.h>

typedef __bf16 bf8 __attribute__((ext_vector_type(8)));
typedef unsigned short u16x8 __attribute__((ext_vector_type(8)));
typedef float f32x4 __attribute__((ext_vector_type(4)));
typedef float f32x2 __attribute__((ext_vector_type(2)));
typedef unsigned int u32x4 __attribute__((ext_vector_type(4)));

union FragU { u16x8 u; bf8 b; u32x4 q; };
union BiasU { f32x4 f; u32x4 q; };

struct __attribute__((packed, aligned(4))) F4u { float v[4]; };
struct __attribute__((packed, aligned(4))) F2u { float v[2]; };

static __device__ __forceinline__ f32x4 MM(const FragU& a, const FragU& b, f32x4 c) {
  return __builtin_amdgcn_mfma_f32_16x16x32_bf16(a.b, b.b, c, 0, 0, 0);
}

#define NBATCH 524288
#define SPB 64                 // 1 chain/wave x 16 samples x 4 waves
#define NTIL (NBATCH / SPB)    // 8192
#define GRID 1024              // 4 blocks/CU (LDS 37.9KB each), 8 iters/block
#define ITERS (NTIL / GRID)    // 8
#define NFRAG 37

// ============================ PREP KERNEL ============================
__global__ __launch_bounds__(64) void cdann_prep(
    const float* __restrict__ gWf1, const float* __restrict__ gbf1,
    const float* __restrict__ gWf2, const float* __restrict__ gbf2,
    const float* __restrict__ gWt1, const float* __restrict__ gbt1,
    const float* __restrict__ gWt2, const float* __restrict__ gbt2,
    const float* __restrict__ gWp1, const float* __restrict__ gbp1,
    const float* __restrict__ gWp2, const float* __restrict__ gbp2,
    const float* __restrict__ gWp3, const float* __restrict__ gbp3,
    const float* __restrict__ gWc1, const float* __restrict__ gbc1,
    const float* __restrict__ gWc2, const float* __restrict__ gbc2,
    const float* __restrict__ gWc3, const float* __restrict__ gbc3,
    u32x4* __restrict__ ws)
{
  const int lane = (int)threadIdx.x & 63;
  const int fid = (int)blockIdx.x;
  const int g = lane >> 4;
  const int c15 = lane & 15;

  auto colF2 = [](int nt, int m) -> int {
    if (nt < 2) return 8 * (m >> 2) + 4 * nt + (m & 3);
    const int gm = m >> 2, r = m & 3;
    if (gm == 0) return 32 + r;
    if (gm == 1) return 36 + r;
    if (gm == 2 && r < 2) return 40 + r;
    return -1;
  };

  if (fid >= 34) {                       // f2 bias slices (f32x4 per lane)
    const int nt = fid - 34;
    BiasU b;
#pragma unroll
    for (int r = 0; r < 4; ++r) {
      const int col = colF2(nt, g * 4 + r);
      b.f[r] = (col >= 0) ? gbf2[col] : 0.f;
    }
    ws[fid * 64 + lane] = b.q;
    return;
  }

  auto v_f1 = [&](int k, int m, int nt) -> float {
    const int n = 32 * (nt >> 1) + 8 * (m >> 2) + 4 * (nt & 1) + (m & 3);
    if (k < 30) return gWf1[k * 64 + n];
    if (k == 30) return gbf1[n];
    return 0.f;
  };
  auto v_f2 = [&](int k, int m, int nt) -> float {
    const int col = colF2(nt, m);
    return (col >= 0) ? gWf2[k * 42 + col] : 0.f;
  };
  auto ffea = [](int v) -> int {
    if (v < 36) return v;
    if (v == 36) return -2;
    if (v >= 40 && v <= 43) return v - 4;
    if (v == 48 || v == 49) return v - 8;
    return -1;
  };
  auto v_q = [&](int k, int m, int nt) -> float {
    const int i = ffea(k);
    if (i == -1) return 0.f;
    const int gm = m >> 2;
    const int u = 4 * nt + (m & 3);
    const int head = u / 5;
    const int f = 5 * gm + (u % 5);
    if (head == 0) return (i == -2) ? gbt1[f] : gWt1[i * 20 + f];
    if (head == 1) return (i == -2) ? gbp1[f] : gWp1[i * 20 + f];
    if (head == 2) return (i == -2) ? gbc1[f] : gWc1[i * 20 + f];
    return (i == -2) ? gbc1[20 + f] : gWc1[(42 + i) * 20 + f];
  };
  auto v_tp = [&](int k, int m, int nt) -> float {
    const int ks = k >> 5, j = k & 7, gk = (k >> 3) & 3;
    const int gm = m >> 2;
    const int u = 4 * nt + (m & 3);
    const int isP2 = (u < 5);
    const int cp = 5 * gm + u;
    const int isT2 = (!isP2 && gm == 0 && (u == 5 || u == 6));
    const int ct = u - 5;
    if (ks == 0) {
      if (j < 5) { const int i = 5 * gk + j; return isT2 ? gWt2[i * 2 + ct] : 0.f; }
      if (j == 7 && gk == 0) { if (isT2) return gbt2[ct]; if (isP2) return gbp2[cp]; }
      return 0.f;
    } else {
      if (j < 5) { const int i = 5 * gk + j; return isP2 ? gWp2[i * 20 + cp] : 0.f; }
      return 0.f;
    }
  };
  auto v_cc = [&](int k, int m, int nt) -> float {
    const int ks = k >> 5, j = k & 7, gk = (k >> 3) & 3;
    const int gm = m >> 2;
    const int u = 4 * nt + (m & 3);
    const int isE0 = (u < 5);
    const int isE1 = (u >= 5 && u < 10);
    const int c0 = 5 * gm + u;
    const int c1 = 5 * gm + (u - 5);
    if (ks == 0) {
      if (j < 5) { const int i = 5 * gk + j; return isE0 ? gWc2[i * 20 + c0] : 0.f; }
      if (j == 7 && gk == 0) { if (isE0) return gbc2[c0]; if (isE1) return gbc2[20 + c1]; }
      return 0.f;
    } else {
      if (j < 5) { const int i = 5 * gk + j; return isE1 ? gWc2[(20 + i) * 20 + c1] : 0.f; }
      return 0.f;
    }
  };
  auto v_o = [&](int k, int m, int nt) -> float {
    const int ks = k >> 5, j = k & 7, gk = (k >> 3) & 3;
    const int gm = m >> 2, r = m & 3;
    int kind = -1, c = 0;   // 0=pd, 1=cd0, 2=cd1
    if (nt == 0) {
      if (gm == 0) { kind = 0; c = r; }
      else if (gm == 1) { if (r < 2) { kind = 0; c = 4 + r; } else { kind = 1; c = r - 2; } }
      else if (gm == 2) { kind = 1; c = 2 + r; }
      else { kind = 2; c = r; }
    } else {
      if (gm == 0 && r < 2) { kind = 2; c = 4 + r; }
    }
    if (kind < 0) return 0.f;
    if (ks == 0) {
      if (j < 5) { const int i = 5 * gk + j; return (kind == 0) ? gWp3[i * 6 + c] : 0.f; }
      if (j < 7) { const int i = 5 * gk + (j - 5); return (kind == 2) ? gWc3[(20 + i) * 6 + c] : 0.f; }
      if (gk == 0) {
        if (kind == 0) return gbp3[c];
        if (kind == 1) return gbc3[c];
        return gbc3[6 + c];
      }
      return 0.f;
    } else {
      if (j < 5) { const int i = 5 * gk + j; return (kind == 1) ? gWc3[i * 6 + c] : 0.f; }
      const int i = 5 * gk + 2 + (j - 5);
      return (kind == 2) ? gWc3[(20 + i) * 6 + c] : 0.f;
    }
  };

  int ks, nt, which;
  if (fid < 4)       { ks = 0;                nt = fid;            which = 0; }
  else if (fid < 10) { int t = fid - 4;  ks = t / 3; nt = t % 3;   which = 1; }
  else if (fid < 20) { int t = fid - 10; ks = t / 5; nt = t % 5;   which = 2; }
  else if (fid < 24) { int t = fid - 20; ks = t / 2; nt = t % 2;   which = 3; }
  else if (fid < 30) { int t = fid - 24; ks = t / 3; nt = t % 3;   which = 4; }
  else               { int t = fid - 30; ks = t / 2; nt = t % 2;   which = 5; }

  FragU f;
#pragma unroll
  for (int j = 0; j < 8; ++j) {
    const int k = ks * 32 + g * 8 + j;
    float v;
    switch (which) {
      case 0: v = v_f1(k, c15, nt); break;
      case 1: v = v_f2(k, c15, nt); break;
      case 2: v = v_q(k, c15, nt); break;
      case 3: v = v_tp(k, c15, nt); break;
      case 4: v = v_cc(k, c15, nt); break;
      default: v = v_o(k, c15, nt); break;
    }
    f.b[j] = (__bf16)v;
  }
  ws[fid * 64 + lane] = f.q;
}

// ============================ MAIN KERNEL ============================
// All 37 weight fragments in LDS (37.9KB; 4 blocks/CU). ONE chain per wave
// keeps working state ~45 VGPR, fitting the 64V+64A budget that
// __launch_bounds__(256,4) imposes -> 4 waves/SIMD (R12 proved occupancy
// rises; it spilled only because NCH=2 state needed ~110 regs).
__global__ __launch_bounds__(256, 4) void cdann_fwd(
    const float* __restrict__ gx, const int* __restrict__ gy,
    const u32x4* __restrict__ ws, float* __restrict__ gout)
{
  __shared__ __align__(16) u32x4 lfr[NFRAG * 64];   // 37888 B
  const int tid = (int)threadIdx.x;
  const int lane = tid & 63;
  const int w = tid >> 6;
  const int g = lane >> 4;
  const int c15 = lane & 15;

  for (int i = tid; i < NFRAG * 64; i += 256) lfr[i] = ws[i];
  __syncthreads();   // lfr read-only afterwards (no more barriers)

  const f32x4 zf = {0.f, 0.f, 0.f, 0.f};
  const __bf16 one = (__bf16)1.0f;
  const __bf16 zero = (__bf16)0.0f;
  float* const outT = gout;
  float* const outP = gout + (size_t)2 * NBATCH;
  float* const outC = gout + (size_t)8 * NBATCH;

  // ---- x/y prefetch (bf16-packed, 4 regs + 1) ----
  FragU bxp;
  int ysp;
  auto loadx = [&](int it) {
    const int s = it * SPB + w * 16 + c15;
    const float* xp = gx + (size_t)s * 30 + g * 8;
    float t[8];
    if (g < 3) {
      F4u a0 = *(const F4u*)xp; F4u a1 = *(const F4u*)(xp + 4);
#pragma unroll
      for (int j = 0; j < 4; ++j) { t[j] = a0.v[j]; t[4 + j] = a1.v[j]; }
    } else {
      F4u a0 = *(const F4u*)xp; F2u a1 = *(const F2u*)(xp + 4);
#pragma unroll
      for (int j = 0; j < 4; ++j) t[j] = a0.v[j];
      t[4] = a1.v[0]; t[5] = a1.v[1];
      t[6] = 1.0f; t[7] = 0.0f;   // k=30 const1 (bias fold), k=31 zero
    }
#pragma unroll
    for (int j = 0; j < 8; ++j) bxp.b[j] = (__bf16)t[j];
    ysp = gy[s];
  };

  loadx((int)blockIdx.x);

  for (int ii = 0; ii < ITERS; ++ii) {
    const int it = (int)blockIdx.x + ii * GRID;
    const int s = it * SPB + w * 16 + c15;

    FragU bx = bxp;
    const int y = ysp;

    if (ii + 1 < ITERS) loadx(it + GRID);   // next iter's loads fly under compute

    // Opaque lane offset: defeats LICM hoisting of the 37 loop-invariant
    // LDS fragment reads into (nonexistent) spare registers.
    int ofs = lane;
    asm volatile("" : "+v"(ofs));
    auto LF = [&](int fid) { FragU t; t.q = lfr[fid * 64 + ofs]; return t; };

    // ---- f1 ----
    f32x4 aH[4];
#pragma unroll
    for (int nt = 0; nt < 4; ++nt) aH[nt] = MM(LF(nt), bx, zf);
    FragU bh0, bh1;
#pragma unroll
    for (int j = 0; j < 8; ++j) {
      bh0.b[j] = (__bf16)fmaxf(aH[j >> 2][j & 3], 0.f);
      bh1.b[j] = (__bf16)fmaxf(aH[2 + (j >> 2)][j & 3], 0.f);
    }

    // ---- f2 ----
    f32x4 aF[3];
#pragma unroll
    for (int nt = 0; nt < 3; ++nt)
      aF[nt] = MM(LF(7 + nt), bh1, MM(LF(4 + nt), bh0, zf));
    FragU bf0, bf1;
    {
      BiasU b0, b1, b2;
      b0.q = lfr[34 * 64 + ofs]; b1.q = lfr[35 * 64 + ofs]; b2.q = lfr[36 * 64 + ofs];
#pragma unroll
      for (int j = 0; j < 8; ++j) {
        const float bb = (j >> 2) ? b1.f[j & 3] : b0.f[j & 3];
        bf0.b[j] = (__bf16)fmaxf(aF[j >> 2][j & 3] + bb, 0.f);
      }
#pragma unroll
      for (int j = 0; j < 4; ++j)
        bf1.b[j] = (__bf16)fmaxf(aF[2][j] + b2.f[j], 0.f);
      bf1.b[4] = (g == 0) ? one : zero;   // v=36: const1 (head-bias row)
      bf1.b[5] = zero; bf1.b[6] = zero; bf1.b[7] = zero;
    }

    // ---- quad heads ----
    f32x4 aQ[5];
#pragma unroll
    for (int nt = 0; nt < 5; ++nt)
      aQ[nt] = MM(LF(15 + nt), bf1, MM(LF(10 + nt), bf0, zf));
    FragU tp0, tp1, cc0, cc1;
    {
      const __bf16 c1v = (g == 0) ? one : zero;
      auto rq = [&](int u) { return (__bf16)fmaxf(aQ[u >> 2][u & 3], 0.f); };
#pragma unroll
      for (int j = 0; j < 5; ++j) {
        tp0.b[j] = rq(j);
        tp1.b[j] = rq(5 + j);
        cc0.b[j] = rq(10 + j);
        cc1.b[j] = rq(15 + j);
      }
      tp0.b[5] = zero; tp0.b[6] = zero; tp0.b[7] = c1v;
      tp1.b[5] = zero; tp1.b[6] = zero; tp1.b[7] = zero;
      cc0.b[5] = zero; cc0.b[6] = zero; cc0.b[7] = c1v;
      cc1.b[5] = zero; cc1.b[6] = zero; cc1.b[7] = zero;
    }

    // ---- [t2|p2] and [c2e0|c2e1] ----
    f32x4 aT[2];
#pragma unroll
    for (int nt = 0; nt < 2; ++nt)
      aT[nt] = MM(LF(22 + nt), tp1, MM(LF(20 + nt), tp0, zf));
    f32x4 aC[3];
#pragma unroll
    for (int nt = 0; nt < 3; ++nt)
      aC[nt] = MM(LF(27 + nt), cc1, MM(LF(24 + nt), cc0, zf));

    // ---- final B-frags ----
    FragU f50, f51;
    f32x2 t2v;
#pragma unroll
    for (int j = 0; j < 4; ++j) {
      f50.b[j] = (__bf16)fmaxf(aT[0][j], 0.f);
      f51.b[j] = (__bf16)fmaxf(aC[0][j], 0.f);
    }
    f50.b[4] = (__bf16)fmaxf(aT[1][0], 0.f);
    f50.b[5] = (__bf16)fmaxf(aC[1][1], 0.f);
    f50.b[6] = (__bf16)fmaxf(aC[1][2], 0.f);
    f50.b[7] = (g == 0) ? one : zero;
    f51.b[4] = (__bf16)fmaxf(aC[1][0], 0.f);
    f51.b[5] = (__bf16)fmaxf(aC[1][3], 0.f);
    f51.b[6] = (__bf16)fmaxf(aC[2][0], 0.f);
    f51.b[7] = (__bf16)fmaxf(aC[2][1], 0.f);
    t2v[0] = aT[1][1]; t2v[1] = aT[1][2];

    // ---- [pd|cd0|cd1] ----
    f32x4 aO0 = MM(LF(32), f51, MM(LF(30), f50, zf));
    f32x4 aO1 = MM(LF(33), f51, MM(LF(31), f50, zf));

    // ---- stores ----
    if (g == 0) {
      *(f32x2*)(outT + (size_t)s * 2) = t2v;
      f32x2 pa = {aO0[0], aO0[1]}, pb = {aO0[2], aO0[3]};
      *(f32x2*)(outP + (size_t)s * 6) = pa;
      *(f32x2*)(outP + (size_t)s * 6 + 2) = pb;
      if (y) { f32x2 cv = {aO1[0], aO1[1]}; *(f32x2*)(outC + (size_t)s * 6 + 4) = cv; }
    } else if (g == 1) {
      f32x2 pc = {aO0[0], aO0[1]};
      *(f32x2*)(outP + (size_t)s * 6 + 4) = pc;
      if (!y) { f32x2 cv = {aO0[2], aO0[3]}; *(f32x2*)(outC + (size_t)s * 6) = cv; }
    } else if (g == 2) {
      if (!y) {
        f32x2 ca = {aO0[0], aO0[1]}, cb = {aO0[2], aO0[3]};
        *(f32x2*)(outC + (size_t)s * 6 + 2) = ca;
        *(f32x2*)(outC + (size_t)s * 6 + 4) = cb;
      }
    } else {
      if (y) {
        f32x2 ca = {aO0[0], aO0[1]}, cb = {aO0[2], aO0[3]};
        *(f32x2*)(outC + (size_t)s * 6) = ca;
        *(f32x2*)(outC + (size_t)s * 6 + 2) = cb;
      }
    }
  }
}

extern "C" void kernel_launch(void* const* d_in, const int* in_sizes, int n_in,
                              void* d_out, int out_size, void* d_ws, size_t ws_size,
                              hipStream_t stream) {
  (void)in_sizes; (void)n_in; (void)ws_size; (void)out_size;
  const float* gx  = (const float*)d_in[0];
  const int*   gy  = (const int*)d_in[1];
  const float* Wf1 = (const float*)d_in[2];  const float* bf1 = (const float*)d_in[3];
  const float* Wf2 = (const float*)d_in[4];  const float* bf2 = (const float*)d_in[5];
  const float* Wt1 = (const float*)d_in[6];  const float* bt1 = (const float*)d_in[7];
  const float* Wt2 = (const float*)d_in[8];  const float* bt2 = (const float*)d_in[9];
  const float* Wp1 = (const float*)d_in[10]; const float* bp1 = (const float*)d_in[11];
  const float* Wp2 = (const float*)d_in[12]; const float* bp2 = (const float*)d_in[13];
  const float* Wp3 = (const float*)d_in[14]; const float* bp3 = (const float*)d_in[15];
  const float* Wc1 = (const float*)d_in[16]; const float* bc1 = (const float*)d_in[17];
  const float* Wc2 = (const float*)d_in[18]; const float* bc2 = (const float*)d_in[19];
  const float* Wc3 = (const float*)d_in[20]; const float* bc3 = (const float*)d_in[21];
  float* out = (float*)d_out;
  u32x4* ws = (u32x4*)d_ws;

  cdann_prep<<<dim3(NFRAG), dim3(64), 0, stream>>>(
      Wf1, bf1, Wf2, bf2, Wt1, bt1, Wt2, bt2,
      Wp1, bp1, Wp2, bp2, Wp3, bp3, Wc1, bc1, Wc2, bc2, Wc3, bc3, ws);

  cdann_fwd<<<dim3(GRID), dim3(256), 0, stream>>>(gx, gy, ws, out);
}